// Round 1
// baseline (123.150 us; speedup 1.0000x reference)
//
#include <hip/hip_runtime.h>

#define N_SEL   8192
#define N_FEAT  256
#define K_SUB   256
#define N_PERS  4
#define E_FULL  262144
#define E_RAW   262144
#define N_TOTAL 8192
#define EPSILON 0.5f
#define LAMB1   0.5f

// Workspace layout:
//  [0, 128KB)        : invn[N_SEL][4]  (f32)  1/(||x[n]*w[p]||+1e-12)
//  [128KB, 129KB)    : score[K_SUB]    (f32)  normalized subgraph scores
//  [256KB, 256KB+8MB): dedup bitmap (N_SEL*N_SEL bits)
#define WS_SCORE_OFF  131072
#define WS_BITMAP_OFF 262144

// ---------------- score normalization (one block) ----------------
__global__ __launch_bounds__(256) void score_kernel(const float* __restrict__ s,
                                                    const int* __restrict__ belong,
                                                    float* __restrict__ score) {
    __shared__ float ssum[K_SUB];
    int t = threadIdx.x;
    ssum[t] = 0.0f;
    __syncthreads();
    atomicAdd(&ssum[belong[t]], s[t]);
    __syncthreads();
    score[t] = s[t] / ssum[belong[t]];
}

// ---------------- per-(node,perspective) inverse norms ----------------
// one wave per (n,p); lane handles 4 dims via float4
__global__ __launch_bounds__(256) void norms_kernel(const float4* __restrict__ x4,
                                                    const float4* __restrict__ w4,
                                                    float* __restrict__ invn) {
    int wave = (blockIdx.x * 256 + threadIdx.x) >> 6;
    int lane = threadIdx.x & 63;
    int n = wave >> 2;
    int p = wave & 3;
    float4 xv = x4[(size_t)n * 64 + lane];
    float4 wv = w4[p * 64 + lane];
    float a = xv.x * wv.x, b = xv.y * wv.y, c = xv.z * wv.z, d = xv.w * wv.w;
    float s = a * a + b * b + c * c + d * d;
    #pragma unroll
    for (int off = 32; off; off >>= 1) s += __shfl_xor(s, off);
    if (lane == 0) invn[n * 4 + p] = 1.0f / (sqrtf(s) + 1e-12f);
}

// ---------------- masked-edge weighted cosine + scatter ----------------
// one wave per edge (grid-stride); lane handles 4 dims x 4 perspectives
__global__ __launch_bounds__(256) void edge_kernel(const float4* __restrict__ x4,
                                                   const float4* __restrict__ w4,
                                                   const int* __restrict__ fe,
                                                   const int* __restrict__ sel_map,
                                                   const int* __restrict__ sel_batch,
                                                   const float4* __restrict__ invn4,
                                                   const float* __restrict__ score,
                                                   unsigned int* __restrict__ bitmap,
                                                   float* __restrict__ out) {
    int lane   = threadIdx.x & 63;
    int waveId = (blockIdx.x * blockDim.x + threadIdx.x) >> 6;
    int nWaves = (gridDim.x * blockDim.x) >> 6;

    // per-lane squared weights for its 4 dims, all 4 perspectives (loaded once)
    float4 q0 = w4[0 * 64 + lane];
    float4 q1 = w4[1 * 64 + lane];
    float4 q2 = w4[2 * 64 + lane];
    float4 q3 = w4[3 * 64 + lane];
    q0.x *= q0.x; q0.y *= q0.y; q0.z *= q0.z; q0.w *= q0.w;
    q1.x *= q1.x; q1.y *= q1.y; q1.z *= q1.z; q1.w *= q1.w;
    q2.x *= q2.x; q2.y *= q2.y; q2.z *= q2.z; q2.w *= q2.w;
    q3.x *= q3.x; q3.y *= q3.y; q3.z *= q3.z; q3.w *= q3.w;

    for (int e = waveId; e < E_FULL; e += nWaves) {
        int i = fe[e];
        int j = fe[E_FULL + e];

        // dedup (mask .set(1.0) semantics) + diagonal removal, wave-level skip
        int skip = 0;
        if (lane == 0) {
            if (i == j) {
                skip = 1;
            } else {
                unsigned int bitpos = (unsigned int)i * (unsigned int)N_SEL + (unsigned int)j;
                unsigned int m = 1u << (bitpos & 31u);
                unsigned int old = atomicOr(&bitmap[bitpos >> 5], m);
                if (old & m) skip = 1;
            }
        }
        skip = __shfl(skip, 0);
        if (skip) continue;

        float4 xi = x4[(size_t)i * 64 + lane];
        float4 xj = x4[(size_t)j * 64 + lane];
        float px = xi.x * xj.x, py = xi.y * xj.y, pz = xi.z * xj.z, pw = xi.w * xj.w;
        float a0 = px * q0.x + py * q0.y + pz * q0.z + pw * q0.w;
        float a1 = px * q1.x + py * q1.y + pz * q1.z + pw * q1.w;
        float a2 = px * q2.x + py * q2.y + pz * q2.z + pw * q2.w;
        float a3 = px * q3.x + py * q3.y + pz * q3.z + pw * q3.w;

        // fold inverse norms in BEFORE the cross-lane reduce (linear), so we
        // only butterfly one scalar instead of four.
        float4 ii = invn4[i];
        float4 ij = invn4[j];
        float v = a0 * (ii.x * ij.x) + a1 * (ii.y * ij.y) +
                  a2 * (ii.z * ij.z) + a3 * (ii.w * ij.w);
        #pragma unroll
        for (int off = 32; off; off >>= 1) v += __shfl_xor(v, off);

        if (lane == 0) {
            v *= 0.25f;  // mean over N_PERS
            if (v > EPSILON) {
                float wgt = score[sel_batch[i]] * LAMB1;
                atomicAdd(&out[(size_t)sel_map[i] * N_TOTAL + sel_map[j]], v * wgt);
            }
        }
    }
}

// ---------------- raw graph scatter (duplicates accumulate) ----------------
__global__ __launch_bounds__(256) void raw_kernel(const int* __restrict__ re,
                                                  float* __restrict__ out) {
    int t = blockIdx.x * 256 + threadIdx.x;
    if (t < E_RAW) {
        int u = re[t];
        int v = re[E_RAW + t];
        atomicAdd(&out[(size_t)u * N_TOTAL + v], 1.0f - LAMB1);
    }
}

extern "C" void kernel_launch(void* const* d_in, const int* in_sizes, int n_in,
                              void* d_out, int out_size, void* d_ws, size_t ws_size,
                              hipStream_t stream) {
    const float* x        = (const float*)d_in[0];
    const float* mw       = (const float*)d_in[1];
    const int* sel_batch  = (const int*)d_in[2];
    const int* sel_map    = (const int*)d_in[3];
    const int* sel_belong = (const int*)d_in[4];
    const float* sel_score= (const float*)d_in[5];
    const int* fe         = (const int*)d_in[6];
    const int* re         = (const int*)d_in[7];
    float* out            = (float*)d_out;

    char* ws              = (char*)d_ws;
    float* invn           = (float*)ws;
    float* score          = (float*)(ws + WS_SCORE_OFF);
    unsigned int* bitmap  = (unsigned int*)(ws + WS_BITMAP_OFF);

    // zero output (must be exact zeros outside scattered entries, every call)
    hipMemsetAsync(out, 0, (size_t)N_TOTAL * N_TOTAL * sizeof(float), stream);
    // zero dedup bitmap every call (determinism across graph replays)
    hipMemsetAsync(bitmap, 0, ((size_t)N_SEL * N_SEL) / 8, stream);

    norms_kernel<<<(N_SEL * N_PERS * 64) / 256, 256, 0, stream>>>(
        (const float4*)x, (const float4*)mw, invn);
    score_kernel<<<1, 256, 0, stream>>>(sel_score, sel_belong, score);
    edge_kernel<<<2048, 256, 0, stream>>>(
        (const float4*)x, (const float4*)mw, fe, sel_map, sel_batch,
        (const float4*)invn, score, bitmap, out);
    raw_kernel<<<(E_RAW + 255) / 256, 256, 0, stream>>>(re, out);
}